// Round 19
// baseline (126.243 us; speedup 1.0000x reference)
//
#include <hip/hip_runtime.h>
#include <math.h>

#define D_MODEL 1024
#define HEADS 16
#define HEAD_DIM 64
#define SEQ 2048
#define BATCH 2
#define KVT 64
#define QTILE 64   // 4 waves x 16 q-rows; grid 1024 -> 4 blocks/CU, 4 waves/SIMD
#define SCALE_Q 0.18033688f  // 0.125 * log2(e): folded into Q; softmax in log2 domain

typedef __attribute__((ext_vector_type(8))) short bf16x8;
typedef __attribute__((ext_vector_type(4))) float f32x4;

__device__ __forceinline__ short f2bf(float f) {
    union { float f; unsigned u; } v; v.f = f;
    unsigned r = (v.u + 0x7FFFu + ((v.u >> 16) & 1u)) >> 16;
    return (short)r;
}

__device__ __forceinline__ unsigned cvt_pk_bf16(float lo, float hi) {
    unsigned r;
    asm("v_cvt_pk_bf16_f32 %0, %1, %2" : "=v"(r) : "v"(lo), "v"(hi));
    return r;
}

__device__ __forceinline__ float fexp2(float x) {
    float r;
    asm("v_exp_f32 %0, %1" : "=v"(r) : "v"(x));
    return r;
}

// ---------------------------------------------------------------------------
// prep: merged  x->bf16 | weight transpose-convert | mask->float
// ---------------------------------------------------------------------------
__global__ __launch_bounds__(256) void prep(
    const float* __restrict__ x, const float* __restrict__ Wq,
    const float* __restrict__ Wk, const float* __restrict__ Wv,
    const float* __restrict__ Wp, const int* __restrict__ mask,
    short* __restrict__ xb, short* __restrict__ Wqkvt,
    short* __restrict__ Wpt, float* __restrict__ maskf) {
    __shared__ float t[32][33];
    const int bid = blockIdx.x;
    if (bid < 2048) {
        const int i = bid * 256 + threadIdx.x;
        float4 a = ((const float4*)x)[2 * i];
        float4 b = ((const float4*)x)[2 * i + 1];
        short r[8] = {f2bf(a.x), f2bf(a.y), f2bf(a.z), f2bf(a.w),
                      f2bf(b.x), f2bf(b.y), f2bf(b.z), f2bf(b.w)};
        *(uint4*)(xb + 8 * i) = *(uint4*)r;
    } else if (bid < 6144) {
        const int tt = bid - 2048;
        const int z = tt >> 10;
        const int rem = tt & 1023;
        const float* W = z == 0 ? Wq : z == 1 ? Wk : z == 2 ? Wv : Wp;
        short* dst = (z < 3) ? Wqkvt + (size_t)z * 1024 * 1024 : Wpt;
        const int n0 = (rem & 31) * 32, k0 = (rem >> 5) * 32;
        const int tx = threadIdx.x & 31, ty = threadIdx.x >> 5;
#pragma unroll
        for (int j = 0; j < 4; ++j)
            t[ty + j * 8][tx] = W[(size_t)(k0 + ty + j * 8) * 1024 + n0 + tx];
        __syncthreads();
#pragma unroll
        for (int j = 0; j < 4; ++j) {
            const int n = ty + j * 8;
            dst[(size_t)(n0 + n) * 1024 + k0 + tx] = f2bf(t[tx][n]);
        }
    } else {
        const int i = (bid - 6144) * 256 + threadIdx.x;
        maskf[i] = mask[i] ? 0.f : -INFINITY;
    }
}

// ---------------------------------------------------------------------------
// bf16 MFMA GEMM (r12 winner, unchanged): 128x128 tile, BK=32, dbuf
// global_load_lds staging, XCD-aware bijective block swizzle.
// MODE 0: f32 out [M,N]. MODE 1: QKV fused; Q scaled, V written transposed.
// ---------------------------------------------------------------------------
template <int MODE>
__global__ __launch_bounds__(256) void mfma_gemm(
    const short* __restrict__ A, const short* __restrict__ Bt,
    const float* __restrict__ b0, const float* __restrict__ b1,
    const float* __restrict__ b2, float* __restrict__ outf,
    short* __restrict__ o0, short* __restrict__ o1, short* __restrict__ o2,
    int M, int N, int K) {
    __shared__ short As[2 * 128 * 32];
    __shared__ short Bs[2 * 128 * 32];

    const int tid = threadIdx.x;
    const int wave = tid >> 6, lane = tid & 63;
    const int l15 = lane & 15, lhi = lane >> 4;
    const int wm = wave >> 1, wn = wave & 1;

    const int nwgx = gridDim.x;
    const int nwg = nwgx * gridDim.y;
    const int lin = blockIdx.y * nwgx + blockIdx.x;
    const int swz = (lin & 7) * (nwg >> 3) + (lin >> 3);
    const int bm0 = (swz / nwgx) * 128, bn0 = (swz % nwgx) * 128;

    f32x4 acc[4][4];
#pragma unroll
    for (int m = 0; m < 4; ++m)
#pragma unroll
        for (int n = 0; n < 4; ++n) acc[m][n] = (f32x4){0.f, 0.f, 0.f, 0.f};

#define STAGE_G(buf, kt_)                                                         \
    {                                                                             \
        const int k0 = (kt_) * 32;                                                \
        _Pragma("unroll") for (int p = 0; p < 2; ++p) {                           \
            const int o = (wave * 2 + p) * 64 + lane;                             \
            const int r = o >> 2;                                                 \
            const int gs = (o & 3) ^ ((r >> 1) & 3);                              \
            __builtin_amdgcn_global_load_lds(                                     \
                (const __attribute__((address_space(1))) void*)(                  \
                    A + (size_t)(bm0 + r) * K + k0 + gs * 8),                     \
                (__attribute__((address_space(3))) void*)(                        \
                    As + (size_t)(buf) * 4096 + (wave * 2 + p) * 512),            \
                16, 0, 0);                                                        \
            __builtin_amdgcn_global_load_lds(                                     \
                (const __attribute__((address_space(1))) void*)(                  \
                    Bt + (size_t)(bn0 + r) * K + k0 + gs * 8),                    \
                (__attribute__((address_space(3))) void*)(                        \
                    Bs + (size_t)(buf) * 4096 + (wave * 2 + p) * 512),            \
                16, 0, 0);                                                        \
        }                                                                         \
    }

    const int NT = K / 32;
    STAGE_G(0, 0);
    __syncthreads();
    for (int kt = 0; kt < NT; ++kt) {
        const int cur = kt & 1;
        if (kt + 1 < NT) STAGE_G((kt + 1) & 1, kt + 1);
        bf16x8 af[4], bf[4];
        const int sg = (lhi ^ ((l15 >> 1) & 3)) * 16;
#pragma unroll
        for (int m = 0; m < 4; ++m)
            af[m] = *(const bf16x8*)((char*)As + cur * 8192 +
                                     (wm * 64 + m * 16 + l15) * 64 + sg);
#pragma unroll
        for (int n = 0; n < 4; ++n)
            bf[n] = *(const bf16x8*)((char*)Bs + cur * 8192 +
                                     (wn * 64 + n * 16 + l15) * 64 + sg);
        __builtin_amdgcn_s_setprio(1);
#pragma unroll
        for (int m = 0; m < 4; ++m)
#pragma unroll
            for (int n = 0; n < 4; ++n)
                acc[m][n] = __builtin_amdgcn_mfma_f32_16x16x32_bf16(af[m], bf[n], acc[m][n], 0, 0, 0);
        __builtin_amdgcn_s_setprio(0);
        __syncthreads();
    }
#undef STAGE_G

    const int which = (MODE == 1) ? (bn0 >> 10) : 0;  // block-uniform third
#pragma unroll
    for (int m = 0; m < 4; ++m) {
#pragma unroll
        for (int n = 0; n < 4; ++n) {
            const int col = bn0 + wn * 64 + n * 16 + l15;
            if (MODE == 0) {
#pragma unroll
                for (int rr = 0; rr < 4; ++rr) {
                    const int row = bm0 + wm * 64 + m * 16 + lhi * 4 + rr;
                    outf[(size_t)row * N + col] = acc[m][n][rr] + b0[col];
                }
            } else {
                const int cc = col & 1023;
                const int h = cc >> 6, dh = cc & 63;
                const int row0 = bm0 + wm * 64 + m * 16 + lhi * 4;
                const int b = row0 >> 11, s0 = row0 & (SEQ - 1);
                if (which == 2) {
                    // V transposed [B,H,Dh,S]: rr axis = consecutive s -> 8B pack
                    const float bias = b2[cc];
                    uint2 w;
                    w.x = cvt_pk_bf16(acc[m][n][0] + bias, acc[m][n][1] + bias);
                    w.y = cvt_pk_bf16(acc[m][n][2] + bias, acc[m][n][3] + bias);
                    *(uint2*)(o2 + ((size_t)(b * HEADS + h) * HEAD_DIM + dh) * SEQ + s0) = w;
                } else {
                    const float bias = (which == 0 ? b0 : b1)[cc];
                    short* dst = which == 0 ? o0 : o1;
#pragma unroll
                    for (int rr = 0; rr < 4; ++rr) {
                        float v = acc[m][n][rr] + bias;
                        if (which == 0) v *= SCALE_Q;
                        dst[(((size_t)(b * HEADS + h)) * SEQ + s0 + rr) * HEAD_DIM + dh] = f2bf(v);
                    }
                }
            }
        }
    }
}

// ---------------------------------------------------------------------------
// Flash attention: r8 geometry (wave owns 16 q-rows, QTILE=64) + r14 math
// (no online softmax: p = exp2(s + mask) directly, range-safe; per-lane row
// sums, one shfl pair at the end). LDS 40 KB -> 4 blocks/CU -> 4 waves/SIMD:
// isolates the wave-parallelism axis (the one never tested under r14 math).
// ---------------------------------------------------------------------------
__global__ __launch_bounds__(256, 4) void flash_attn(
    const short* __restrict__ Q, const short* __restrict__ K,
    const short* __restrict__ Vt, const float* __restrict__ maskf,
    short* __restrict__ Y) {
    __shared__ unsigned char kt[2][KVT * 128];       // 16 KB
    __shared__ unsigned char vt[2][HEAD_DIM * 128];  // 16 KB
    __shared__ unsigned char pb[4][16 * 128];        // 8 KB

    const int tid = threadIdx.x;
    const int wave = tid >> 6;
    const int lane = tid & 63;
    const int l15 = lane & 15;
    const int lhi = lane >> 4;

    const int nwg = gridDim.x;   // 1024, divisible by 8
    const int wg = blockIdx.x;
    const int swz = (wg & 7) * (nwg >> 3) + (wg >> 3);
    const int qt = swz & 31;     // SEQ/QTILE = 32
    const int bh = swz >> 5;
    const int b = bh >> 4;

    const int q0 = qt * QTILE + wave * 16;

    const short* Qp = Q + ((size_t)bh * SEQ + q0 + l15) * HEAD_DIM;
    bf16x8 qf[2];
    qf[0] = *(const bf16x8*)(Qp + 8 * lhi);
    qf[1] = *(const bf16x8*)(Qp + 8 * lhi + 32);

    const unsigned char* Kb8 = (const unsigned char*)(K + (size_t)bh * SEQ * HEAD_DIM);
    const unsigned char* Vb8 = (const unsigned char*)(Vt + (size_t)bh * HEAD_DIM * SEQ);
    const float* mb = maskf + b * SEQ;

#define STAGE(buf, kvi)                                                            \
    {                                                                              \
        const unsigned char* kbase = Kb8 + (size_t)(kvi) * KVT * 128;              \
        const unsigned char* vbase = Vb8 + (size_t)(kvi) * 128;                    \
        _Pragma("unroll") for (int p = 0; p < 2; ++p) {                            \
            const int o = (wave * 2 + p) * 64 + lane;                              \
            const int row = o >> 3;                                                \
            const int inner = (o & 7) * 16;                                        \
            const int src = inner ^ ((row & 7) << 4);                              \
            __builtin_amdgcn_global_load_lds(                                      \
                (const __attribute__((address_space(1))) void*)(                   \
                    kbase + row * 128 + src),                                      \
                (__attribute__((address_space(3))) void*)(                         \
                    &kt[buf][(wave * 2 + p) * 1024]),                              \
                16, 0, 0);                                                         \
            __builtin_amdgcn_global_load_lds(                                      \
                (const __attribute__((address_space(1))) void*)(                   \
                    vbase + (size_t)row * (SEQ * 2) + src),                        \
                (__attribute__((address_space(3))) void*)(                         \
                    &vt[buf][(wave * 2 + p) * 1024]),                              \
                16, 0, 0);                                                         \
        }                                                                          \
    }

    f32x4 accO[4];
    float lrow = 0.f;
#pragma unroll
    for (int i = 0; i < 4; ++i) accO[i] = (f32x4){0.f, 0.f, 0.f, 0.f};

    STAGE(0, 0);
    __syncthreads();

    for (int kv = 0; kv < SEQ / KVT; ++kv) {
        const int cur = kv & 1;
        if (kv + 1 < SEQ / KVT) STAGE((kv + 1) & 1, kv + 1);

        const int k0 = kv * KVT;

        // ---- QK^T (swapped): accS[nt][r] = S[key=k0+16nt+4lhi+r][q=q0+l15]
        f32x4 accS[4];
#pragma unroll
        for (int nt = 0; nt < 4; ++nt) accS[nt] = (f32x4){0.f, 0.f, 0.f, 0.f};
#pragma unroll
        for (int c = 0; c < 2; ++c) {
            bf16x8 kf[4];
#pragma unroll
            for (int nt = 0; nt < 4; ++nt) {
                const int key = l15 + 16 * nt;
                kf[nt] = *(const bf16x8*)(kt[cur] + key * 128 +
                                          ((16 * lhi + 64 * c) ^ ((key & 7) << 4)));
            }
            __builtin_amdgcn_s_setprio(1);
#pragma unroll
            for (int nt = 0; nt < 4; ++nt)
                accS[nt] = __builtin_amdgcn_mfma_f32_16x16x32_bf16(kf[nt], qf[c], accS[nt], 0, 0, 0);
            __builtin_amdgcn_s_setprio(0);
        }

        // ---- p = exp2(s + mask); per-lane row sum; pack to per-wave LDS
#pragma unroll
        for (int nt = 0; nt < 4; ++nt) {
            const f32x4 ma = *(const f32x4*)(mb + k0 + 16 * nt + 4 * lhi);
            f32x4 p;
#pragma unroll
            for (int r = 0; r < 4; ++r) {
                p[r] = fexp2(accS[nt][r] + ma[r]);
                lrow += p[r];
            }
            uint2 w;
            w.x = cvt_pk_bf16(p[0], p[1]);
            w.y = cvt_pk_bf16(p[2], p[3]);
            *(uint2*)(pb[wave] + l15 * 128 + ((32 * nt + 8 * lhi) ^ (l15 << 3))) = w;
        }

        // ---- PV (swapped)
#pragma unroll
        for (int c = 0; c < 2; ++c) {
            union { bf16x8 v; uint2 u[2]; } pfu;
            pfu.u[0] = *(const uint2*)(pb[wave] + l15 * 128 +
                                       ((16 * lhi + 64 * c) ^ (l15 << 3)));
            pfu.u[1] = *(const uint2*)(pb[wave] + l15 * 128 +
                                       ((16 * lhi + 64 * c + 8) ^ (l15 << 3)));
            const bf16x8 pf = pfu.v;
            bf16x8 vf[4];
#pragma unroll
            for (int d = 0; d < 4; ++d) {
                const int dh = l15 + 16 * d;
                vf[d] = *(const bf16x8*)(vt[cur] + dh * 128 +
                                         ((16 * lhi + 64 * c) ^ ((dh & 7) << 4)));
            }
            __builtin_amdgcn_s_setprio(1);
#pragma unroll
            for (int d = 0; d < 4; ++d)
                accO[d] = __builtin_amdgcn_mfma_f32_16x16x32_bf16(vf[d], pf, accO[d], 0, 0, 0);
            __builtin_amdgcn_s_setprio(0);
        }
        __syncthreads();
    }
#undef STAGE

    // ---- epilogue: one cross-lane reduce, then packed stores
    float rs = lrow;
    rs += __shfl_xor(rs, 16);
    rs += __shfl_xor(rs, 32);
    const float inv = (rs > 0.f) ? 1.f / rs : 0.f;
    const int qg = q0 + l15;
    short* Yp = Y + ((size_t)b * SEQ + qg) * D_MODEL + (bh & 15) * HEAD_DIM;
#pragma unroll
    for (int d = 0; d < 4; ++d) {
        uint2 w;
        w.x = cvt_pk_bf16(accO[d][0] * inv, accO[d][1] * inv);
        w.y = cvt_pk_bf16(accO[d][2] * inv, accO[d][3] * inv);
        *(uint2*)(Yp + 16 * d + 4 * lhi) = w;
    }
}

// ---------------------------------------------------------------------------
extern "C" void kernel_launch(void* const* d_in, const int* in_sizes, int n_in,
                              void* d_out, int out_size, void* d_ws, size_t ws_size,
                              hipStream_t stream) {
    const float* x    = (const float*)d_in[0];
    const int*   mask = (const int*)  d_in[1];
    const float* Wq   = (const float*)d_in[2];
    const float* bq   = (const float*)d_in[3];
    const float* Wk   = (const float*)d_in[4];
    const float* bk   = (const float*)d_in[5];
    const float* Wv   = (const float*)d_in[6];
    const float* bv   = (const float*)d_in[7];
    const float* Wp   = (const float*)d_in[8];
    const float* bp   = (const float*)d_in[9];
    float* out = (float*)d_out;

    short* ws    = (short*)d_ws;
    short* xb    = ws;                          // 4M shorts
    short* Wqkvt = xb + ((size_t)4 << 20);      // 3M
    short* Wpt   = Wqkvt + ((size_t)3 << 20);   // 1M
    short* Qb    = Wpt + ((size_t)1 << 20);     // 4M
    short* Kb    = Qb + ((size_t)4 << 20);      // 4M
    short* Vtb   = Kb + ((size_t)4 << 20);      // 4M
    short* Yb    = Vtb + ((size_t)4 << 20);     // 4M
    float* maskf = (float*)(Yb + ((size_t)4 << 20));  // 4096 floats

    const int M = BATCH * SEQ;  // 4096

    prep<<<dim3(6160), 256, 0, stream>>>(x, Wq, Wk, Wv, Wp, mask,
                                         xb, Wqkvt, Wpt, maskf);

    mfma_gemm<1><<<dim3(3 * D_MODEL / 128, M / 128), 256, 0, stream>>>(
        xb, Wqkvt, bq, bk, bv, nullptr, Qb, Kb, Vtb, M, 3 * D_MODEL, D_MODEL);

    flash_attn<<<dim3(BATCH * HEADS * (SEQ / QTILE)), 256, 0, stream>>>(Qb, Kb, Vtb, maskf, Yb);

    mfma_gemm<0><<<dim3(D_MODEL / 128, M / 128), 256, 0, stream>>>(
        Yb, Wpt, bp, bp, bp, out, nullptr, nullptr, nullptr, M, D_MODEL, D_MODEL);
}

// Round 20
// 119.079 us; speedup vs baseline: 1.0602x; 1.0602x over previous
//
#include <hip/hip_runtime.h>
#include <math.h>

#define D_MODEL 1024
#define HEADS 16
#define HEAD_DIM 64
#define SEQ 2048
#define BATCH 2
#define KVT 64
#define QTILE 128  // 4 waves x (2 x 16) q-rows
#define SCALE_Q 0.18033688f  // 0.125 * log2(e): folded into Q; softmax in log2 domain

typedef __attribute__((ext_vector_type(8))) short bf16x8;
typedef __attribute__((ext_vector_type(4))) float f32x4;

__device__ __forceinline__ short f2bf(float f) {
    union { float f; unsigned u; } v; v.f = f;
    unsigned r = (v.u + 0x7FFFu + ((v.u >> 16) & 1u)) >> 16;
    return (short)r;
}

__device__ __forceinline__ unsigned cvt_pk_bf16(float lo, float hi) {
    unsigned r;
    asm("v_cvt_pk_bf16_f32 %0, %1, %2" : "=v"(r) : "v"(lo), "v"(hi));
    return r;
}

__device__ __forceinline__ float fexp2(float x) {
    float r;
    asm("v_exp_f32 %0, %1" : "=v"(r) : "v"(x));
    return r;
}

// ---------------------------------------------------------------------------
// prep: merged  x->bf16 | weight transpose-convert | mask->float
// ---------------------------------------------------------------------------
__global__ __launch_bounds__(256) void prep(
    const float* __restrict__ x, const float* __restrict__ Wq,
    const float* __restrict__ Wk, const float* __restrict__ Wv,
    const float* __restrict__ Wp, const int* __restrict__ mask,
    short* __restrict__ xb, short* __restrict__ Wqkvt,
    short* __restrict__ Wpt, float* __restrict__ maskf) {
    __shared__ float t[32][33];
    const int bid = blockIdx.x;
    if (bid < 2048) {
        const int i = bid * 256 + threadIdx.x;
        float4 a = ((const float4*)x)[2 * i];
        float4 b = ((const float4*)x)[2 * i + 1];
        short r[8] = {f2bf(a.x), f2bf(a.y), f2bf(a.z), f2bf(a.w),
                      f2bf(b.x), f2bf(b.y), f2bf(b.z), f2bf(b.w)};
        *(uint4*)(xb + 8 * i) = *(uint4*)r;
    } else if (bid < 6144) {
        const int tt = bid - 2048;
        const int z = tt >> 10;
        const int rem = tt & 1023;
        const float* W = z == 0 ? Wq : z == 1 ? Wk : z == 2 ? Wv : Wp;
        short* dst = (z < 3) ? Wqkvt + (size_t)z * 1024 * 1024 : Wpt;
        const int n0 = (rem & 31) * 32, k0 = (rem >> 5) * 32;
        const int tx = threadIdx.x & 31, ty = threadIdx.x >> 5;
#pragma unroll
        for (int j = 0; j < 4; ++j)
            t[ty + j * 8][tx] = W[(size_t)(k0 + ty + j * 8) * 1024 + n0 + tx];
        __syncthreads();
#pragma unroll
        for (int j = 0; j < 4; ++j) {
            const int n = ty + j * 8;
            dst[(size_t)(n0 + n) * 1024 + k0 + tx] = f2bf(t[tx][n]);
        }
    } else {
        const int i = (bid - 6144) * 256 + threadIdx.x;
        maskf[i] = mask[i] ? 0.f : -INFINITY;
    }
}

// ---------------------------------------------------------------------------
// bf16 MFMA GEMM (r12 winner, unchanged): 128x128 tile, BK=32, dbuf
// global_load_lds staging, XCD-aware bijective block swizzle.
// MODE 0: f32 out [M,N]. MODE 1: QKV fused; Q scaled, V written transposed.
// ---------------------------------------------------------------------------
template <int MODE>
__global__ __launch_bounds__(256) void mfma_gemm(
    const short* __restrict__ A, const short* __restrict__ Bt,
    const float* __restrict__ b0, const float* __restrict__ b1,
    const float* __restrict__ b2, float* __restrict__ outf,
    short* __restrict__ o0, short* __restrict__ o1, short* __restrict__ o2,
    int M, int N, int K) {
    __shared__ short As[2 * 128 * 32];
    __shared__ short Bs[2 * 128 * 32];

    const int tid = threadIdx.x;
    const int wave = tid >> 6, lane = tid & 63;
    const int l15 = lane & 15, lhi = lane >> 4;
    const int wm = wave >> 1, wn = wave & 1;

    const int nwgx = gridDim.x;
    const int nwg = nwgx * gridDim.y;
    const int lin = blockIdx.y * nwgx + blockIdx.x;
    const int swz = (lin & 7) * (nwg >> 3) + (lin >> 3);
    const int bm0 = (swz / nwgx) * 128, bn0 = (swz % nwgx) * 128;

    f32x4 acc[4][4];
#pragma unroll
    for (int m = 0; m < 4; ++m)
#pragma unroll
        for (int n = 0; n < 4; ++n) acc[m][n] = (f32x4){0.f, 0.f, 0.f, 0.f};

#define STAGE_G(buf, kt_)                                                         \
    {                                                                             \
        const int k0 = (kt_) * 32;                                                \
        _Pragma("unroll") for (int p = 0; p < 2; ++p) {                           \
            const int o = (wave * 2 + p) * 64 + lane;                             \
            const int r = o >> 2;                                                 \
            const int gs = (o & 3) ^ ((r >> 1) & 3);                              \
            __builtin_amdgcn_global_load_lds(                                     \
                (const __attribute__((address_space(1))) void*)(                  \
                    A + (size_t)(bm0 + r) * K + k0 + gs * 8),                     \
                (__attribute__((address_space(3))) void*)(                        \
                    As + (size_t)(buf) * 4096 + (wave * 2 + p) * 512),            \
                16, 0, 0);                                                        \
            __builtin_amdgcn_global_load_lds(                                     \
                (const __attribute__((address_space(1))) void*)(                  \
                    Bt + (size_t)(bn0 + r) * K + k0 + gs * 8),                    \
                (__attribute__((address_space(3))) void*)(                        \
                    Bs + (size_t)(buf) * 4096 + (wave * 2 + p) * 512),            \
                16, 0, 0);                                                        \
        }                                                                         \
    }

    const int NT = K / 32;
    STAGE_G(0, 0);
    __syncthreads();
    for (int kt = 0; kt < NT; ++kt) {
        const int cur = kt & 1;
        if (kt + 1 < NT) STAGE_G((kt + 1) & 1, kt + 1);
        bf16x8 af[4], bf[4];
        const int sg = (lhi ^ ((l15 >> 1) & 3)) * 16;
#pragma unroll
        for (int m = 0; m < 4; ++m)
            af[m] = *(const bf16x8*)((char*)As + cur * 8192 +
                                     (wm * 64 + m * 16 + l15) * 64 + sg);
#pragma unroll
        for (int n = 0; n < 4; ++n)
            bf[n] = *(const bf16x8*)((char*)Bs + cur * 8192 +
                                     (wn * 64 + n * 16 + l15) * 64 + sg);
        __builtin_amdgcn_s_setprio(1);
#pragma unroll
        for (int m = 0; m < 4; ++m)
#pragma unroll
            for (int n = 0; n < 4; ++n)
                acc[m][n] = __builtin_amdgcn_mfma_f32_16x16x32_bf16(af[m], bf[n], acc[m][n], 0, 0, 0);
        __builtin_amdgcn_s_setprio(0);
        __syncthreads();
    }
#undef STAGE_G

    const int which = (MODE == 1) ? (bn0 >> 10) : 0;  // block-uniform third
#pragma unroll
    for (int m = 0; m < 4; ++m) {
#pragma unroll
        for (int n = 0; n < 4; ++n) {
            const int col = bn0 + wn * 64 + n * 16 + l15;
            if (MODE == 0) {
#pragma unroll
                for (int rr = 0; rr < 4; ++rr) {
                    const int row = bm0 + wm * 64 + m * 16 + lhi * 4 + rr;
                    outf[(size_t)row * N + col] = acc[m][n][rr] + b0[col];
                }
            } else {
                const int cc = col & 1023;
                const int h = cc >> 6, dh = cc & 63;
                const int row0 = bm0 + wm * 64 + m * 16 + lhi * 4;
                const int b = row0 >> 11, s0 = row0 & (SEQ - 1);
                if (which == 2) {
                    // V transposed [B,H,Dh,S]: rr axis = consecutive s -> 8B pack
                    const float bias = b2[cc];
                    uint2 w;
                    w.x = cvt_pk_bf16(acc[m][n][0] + bias, acc[m][n][1] + bias);
                    w.y = cvt_pk_bf16(acc[m][n][2] + bias, acc[m][n][3] + bias);
                    *(uint2*)(o2 + ((size_t)(b * HEADS + h) * HEAD_DIM + dh) * SEQ + s0) = w;
                } else {
                    const float bias = (which == 0 ? b0 : b1)[cc];
                    short* dst = which == 0 ? o0 : o1;
#pragma unroll
                    for (int rr = 0; rr < 4; ++rr) {
                        float v = acc[m][n][rr] + bias;
                        if (which == 0) v *= SCALE_Q;
                        dst[(((size_t)(b * HEADS + h)) * SEQ + s0 + rr) * HEAD_DIM + dh] = f2bf(v);
                    }
                }
            }
        }
    }
}

// ---------------------------------------------------------------------------
// Flash attention, T15 two-tile pipeline (r17 best-measured configuration):
//  QK MFMA results for tile kv are consumed at tile kv+1. accS ping-pongs
//  between NAMED accA/accB (2 tiles/iteration). V triple-buffered; K double-
//  buffered; mask staged once to LDS; counted vmcnt(4); raw barriers.
// ---------------------------------------------------------------------------
__global__ __launch_bounds__(256, 2) void flash_attn(
    const short* __restrict__ Q, const short* __restrict__ K,
    const short* __restrict__ Vt, const float* __restrict__ maskf,
    short* __restrict__ Y) {
    __shared__ unsigned char kt[2][KVT * 128];       // 16 KB
    __shared__ unsigned char vt[3][KVT * 128];       // 24 KB (triple buffer)
    __shared__ unsigned char pb[4][32 * 128];        // 16 KB (wave-private)
    __shared__ float mask_lds[SEQ];                  // 8 KB

    const int tid = threadIdx.x;
    const int wave = tid >> 6;
    const int lane = tid & 63;
    const int l15 = lane & 15;
    const int lhi = lane >> 4;

    const int nwg = gridDim.x;   // 512, divisible by 8
    const int wg = blockIdx.x;
    const int swz = (wg & 7) * (nwg >> 3) + (wg >> 3);
    const int qt = swz & 15;     // SEQ/QTILE = 16
    const int bh = swz >> 4;
    const int b = bh >> 4;

    const int q0 = qt * QTILE + wave * 32;

    bf16x8 qf[2][2];
#pragma unroll
    for (int qi = 0; qi < 2; ++qi) {
        const short* Qp = Q + ((size_t)bh * SEQ + q0 + 16 * qi + l15) * HEAD_DIM;
        qf[qi][0] = *(const bf16x8*)(Qp + 8 * lhi);
        qf[qi][1] = *(const bf16x8*)(Qp + 8 * lhi + 32);
    }

    const unsigned char* Kb8 = (const unsigned char*)(K + (size_t)bh * SEQ * HEAD_DIM);
    const unsigned char* Vb8 = (const unsigned char*)(Vt + (size_t)bh * HEAD_DIM * SEQ);
    const float* mb = maskf + b * SEQ;

#define STAGE(kbuf, vbuf, kvi)                                                     \
    {                                                                              \
        const unsigned char* kbase = Kb8 + (size_t)(kvi) * KVT * 128;              \
        const unsigned char* vbase = Vb8 + (size_t)(kvi) * 128;                    \
        _Pragma("unroll") for (int p = 0; p < 2; ++p) {                            \
            const int o = (wave * 2 + p) * 64 + lane;                              \
            const int row = o >> 3;                                                \
            const int inner = (o & 7) * 16;                                        \
            const int src = inner ^ ((row & 7) << 4);                              \
            __builtin_amdgcn_global_load_lds(                                      \
                (const __attribute__((address_space(1))) void*)(                   \
                    kbase + row * 128 + src),                                      \
                (__attribute__((address_space(3))) void*)(                         \
                    &kt[kbuf][(wave * 2 + p) * 1024]),                             \
                16, 0, 0);                                                         \
            __builtin_amdgcn_global_load_lds(                                      \
                (const __attribute__((address_space(1))) void*)(                   \
                    vbase + (size_t)row * (SEQ * 2) + src),                        \
                (__attribute__((address_space(3))) void*)(                         \
                    &vt[vbuf][(wave * 2 + p) * 1024]),                             \
                16, 0, 0);                                                         \
        }                                                                          \
    }

    f32x4 accA[2][4], accB[2][4], accO[2][4];
    float lrow[2] = {0.f, 0.f};
#pragma unroll
    for (int qi = 0; qi < 2; ++qi)
#pragma unroll
        for (int i = 0; i < 4; ++i) accO[qi][i] = (f32x4){0.f, 0.f, 0.f, 0.f};

    // ---- prologue: mask -> LDS, stage tile 0, drain, QK(0) -> accA
    {
        const unsigned char* msrc = (const unsigned char*)mb;
#pragma unroll
        for (int p = 0; p < 2; ++p) {
            __builtin_amdgcn_global_load_lds(
                (const __attribute__((address_space(1))) void*)(
                    msrc + ((wave * 2 + p) * 64 + lane) * 16),
                (__attribute__((address_space(3))) void*)(
                    (unsigned char*)mask_lds + (wave * 2 + p) * 1024),
                16, 0, 0);
        }
    }
    STAGE(0, 0, 0);
    asm volatile("s_waitcnt vmcnt(0)" ::: "memory");
    __builtin_amdgcn_sched_barrier(0);
    __builtin_amdgcn_s_barrier();
    STAGE(1, 1, 1);
    {
        const unsigned char* ktb = kt[0];
        bf16x8 kf0[4], kf1[4];
#pragma unroll
        for (int nt = 0; nt < 4; ++nt) {
            const int key = l15 + 16 * nt;
            kf0[nt] = *(const bf16x8*)(ktb + key * 128 + ((16 * lhi) ^ ((key & 7) << 4)));
            kf1[nt] = *(const bf16x8*)(ktb + key * 128 + ((16 * lhi + 64) ^ ((key & 7) << 4)));
        }
#pragma unroll
        for (int qi = 0; qi < 2; ++qi)
#pragma unroll
            for (int nt = 0; nt < 4; ++nt) {
                f32x4 t0 = __builtin_amdgcn_mfma_f32_16x16x32_bf16(
                    kf0[nt], qf[qi][0], (f32x4){0.f, 0.f, 0.f, 0.f}, 0, 0, 0);
                accA[qi][nt] = __builtin_amdgcn_mfma_f32_16x16x32_bf16(
                    kf1[nt], qf[qi][1], t0, 0, 0, 0);
            }
    }
    __builtin_amdgcn_s_barrier();

    // BODY(kv): QK(kv) -> CUR; softmax+PV(kv-1) from PRV.
#define BODY(kv, CUR, PRV, DO_STAGE)                                               \
    {                                                                              \
        if (DO_STAGE) {                                                            \
            STAGE(((kv) + 1) & 1, ((kv) + 1) % 3, (kv) + 1);                       \
            asm volatile("s_waitcnt vmcnt(4)" ::: "memory");                       \
        } else {                                                                   \
            asm volatile("s_waitcnt vmcnt(0)" ::: "memory");                       \
        }                                                                          \
        __builtin_amdgcn_sched_barrier(0);                                         \
        __builtin_amdgcn_s_barrier();                                              \
        bf16x8 kf0[4], kf1[4];                                                     \
        {                                                                          \
            const unsigned char* ktb = kt[(kv) & 1];                               \
            _Pragma("unroll") for (int nt = 0; nt < 4; ++nt) {                     \
                const int key = l15 + 16 * nt;                                     \
                kf0[nt] = *(const bf16x8*)(ktb + key * 128 +                       \
                                           ((16 * lhi) ^ ((key & 7) << 4)));       \
                kf1[nt] = *(const bf16x8*)(ktb + key * 128 +                       \
                                           ((16 * lhi + 64) ^ ((key & 7) << 4)));  \
            }                                                                      \
        }                                                                          \
        /* softmax of tile kv-1 (registers only; covers kf lgkm latency) */        \
        f32x4 ma[4];                                                               \
        _Pragma("unroll") for (int nt = 0; nt < 4; ++nt)                           \
            ma[nt] = *(const f32x4*)(&mask_lds[((kv) - 1) * 64 + 16 * nt + 4 * lhi]); \
        _Pragma("unroll") for (int qi = 0; qi < 2; ++qi) {                         \
            _Pragma("unroll") for (int nt = 0; nt < 4; ++nt) {                     \
                f32x4 p;                                                           \
                _Pragma("unroll") for (int r = 0; r < 4; ++r) {                    \
                    p[r] = fexp2(PRV[qi][nt][r] + ma[nt][r]);                      \
                    lrow[qi] += p[r];                                              \
                }                                                                  \
                uint2 w;                                                           \
                w.x = cvt_pk_bf16(p[0], p[1]);                                     \
                w.y = cvt_pk_bf16(p[2], p[3]);                                     \
                *(uint2*)(pb[wave] + (l15 + 16 * qi) * 128 +                       \
                          ((32 * nt + 8 * lhi) ^ (l15 << 3))) = w;                 \
            }                                                                      \
        }                                                                          \
        /* QK MFMAs for tile kv (results consumed next tile) */                    \
        __builtin_amdgcn_s_setprio(1);                                             \
        _Pragma("unroll") for (int qi = 0; qi < 2; ++qi)                           \
            _Pragma("unroll") for (int nt = 0; nt < 4; ++nt) {                     \
                f32x4 t0 = __builtin_amdgcn_mfma_f32_16x16x32_bf16(                \
                    kf0[nt], qf[qi][0], (f32x4){0.f, 0.f, 0.f, 0.f}, 0, 0, 0);     \
                CUR[qi][nt] = __builtin_amdgcn_mfma_f32_16x16x32_bf16(             \
                    kf1[nt], qf[qi][1], t0, 0, 0, 0);                              \
            }                                                                      \
        __builtin_amdgcn_s_setprio(0);                                             \
        /* PV for tile kv-1 */                                                     \
        {                                                                          \
            const unsigned char* vtb = vt[((kv) - 1) % 3];                         \
            _Pragma("unroll") for (int c = 0; c < 2; ++c) {                        \
                bf16x8 pf[2];                                                      \
                _Pragma("unroll") for (int qi = 0; qi < 2; ++qi) {                 \
                    union { bf16x8 v; uint2 u[2]; } pfu;                           \
                    pfu.u[0] = *(const uint2*)(pb[wave] + (l15 + 16 * qi) * 128 +  \
                                               ((16 * lhi + 64 * c) ^ (l15 << 3))); \
                    pfu.u[1] = *(const uint2*)(pb[wave] + (l15 + 16 * qi) * 128 +  \
                                               ((16 * lhi + 64 * c + 8) ^ (l15 << 3))); \
                    pf[qi] = pfu.v;                                                \
                }                                                                  \
                bf16x8 vf[4];                                                      \
                _Pragma("unroll") for (int d = 0; d < 4; ++d) {                    \
                    const int dh = l15 + 16 * d;                                   \
                    vf[d] = *(const bf16x8*)(vtb + dh * 128 +                      \
                                             ((16 * lhi + 64 * c) ^ ((dh & 7) << 4))); \
                }                                                                  \
                __builtin_amdgcn_s_setprio(1);                                     \
                _Pragma("unroll") for (int qi = 0; qi < 2; ++qi)                   \
                    _Pragma("unroll") for (int d = 0; d < 4; ++d)                  \
                        accO[qi][d] = __builtin_amdgcn_mfma_f32_16x16x32_bf16(     \
                            vf[d], pf[qi], accO[qi][d], 0, 0, 0);                  \
                __builtin_amdgcn_s_setprio(0);                                     \
            }                                                                      \
        }                                                                          \
        __builtin_amdgcn_s_barrier();                                              \
    }

    // tiles 1..30 (two per iteration, static accA/accB ping-pong)
    for (int kv = 1; kv <= 29; kv += 2) {
        BODY(kv, accB, accA, 1);
        BODY(kv + 1, accA, accB, 1);
    }
    // tile 31: last QK, softmax+PV of tile 30
    BODY(31, accB, accA, 0);

    // ---- epilogue: softmax+PV of tile 31 (accB), then reduce + store
    {
        f32x4 ma[4];
#pragma unroll
        for (int nt = 0; nt < 4; ++nt)
            ma[nt] = *(const f32x4*)(&mask_lds[31 * 64 + 16 * nt + 4 * lhi]);
#pragma unroll
        for (int qi = 0; qi < 2; ++qi) {
#pragma unroll
            for (int nt = 0; nt < 4; ++nt) {
                f32x4 p;
#pragma unroll
                for (int r = 0; r < 4; ++r) {
                    p[r] = fexp2(accB[qi][nt][r] + ma[nt][r]);
                    lrow[qi] += p[r];
                }
                uint2 w;
                w.x = cvt_pk_bf16(p[0], p[1]);
                w.y = cvt_pk_bf16(p[2], p[3]);
                *(uint2*)(pb[wave] + (l15 + 16 * qi) * 128 +
                          ((32 * nt + 8 * lhi) ^ (l15 << 3))) = w;
            }
        }
        const unsigned char* vtb = vt[31 % 3];
#pragma unroll
        for (int c = 0; c < 2; ++c) {
            bf16x8 pf[2];
#pragma unroll
            for (int qi = 0; qi < 2; ++qi) {
                union { bf16x8 v; uint2 u[2]; } pfu;
                pfu.u[0] = *(const uint2*)(pb[wave] + (l15 + 16 * qi) * 128 +
                                           ((16 * lhi + 64 * c) ^ (l15 << 3)));
                pfu.u[1] = *(const uint2*)(pb[wave] + (l15 + 16 * qi) * 128 +
                                           ((16 * lhi + 64 * c + 8) ^ (l15 << 3)));
                pf[qi] = pfu.v;
            }
            bf16x8 vf[4];
#pragma unroll
            for (int d = 0; d < 4; ++d) {
                const int dh = l15 + 16 * d;
                vf[d] = *(const bf16x8*)(vtb + dh * 128 +
                                         ((16 * lhi + 64 * c) ^ ((dh & 7) << 4)));
            }
#pragma unroll
            for (int qi = 0; qi < 2; ++qi)
#pragma unroll
                for (int d = 0; d < 4; ++d)
                    accO[qi][d] = __builtin_amdgcn_mfma_f32_16x16x32_bf16(
                        vf[d], pf[qi], accO[qi][d], 0, 0, 0);
        }
    }
#undef BODY
#undef STAGE

#pragma unroll
    for (int qi = 0; qi < 2; ++qi) {
        float rs = lrow[qi];
        rs += __shfl_xor(rs, 16);
        rs += __shfl_xor(rs, 32);
        const float inv = (rs > 0.f) ? 1.f / rs : 0.f;
        const int qg = q0 + 16 * qi + l15;
        short* Yp = Y + ((size_t)b * SEQ + qg) * D_MODEL + (bh & 15) * HEAD_DIM;
#pragma unroll
        for (int d = 0; d < 4; ++d) {
            uint2 w;
            w.x = cvt_pk_bf16(accO[qi][d][0] * inv, accO[qi][d][1] * inv);
            w.y = cvt_pk_bf16(accO[qi][d][2] * inv, accO[qi][d][3] * inv);
            *(uint2*)(Yp + 16 * d + 4 * lhi) = w;
        }
    }
}

// ---------------------------------------------------------------------------
extern "C" void kernel_launch(void* const* d_in, const int* in_sizes, int n_in,
                              void* d_out, int out_size, void* d_ws, size_t ws_size,
                              hipStream_t stream) {
    const float* x    = (const float*)d_in[0];
    const int*   mask = (const int*)  d_in[1];
    const float* Wq   = (const float*)d_in[2];
    const float* bq   = (const float*)d_in[3];
    const float* Wk   = (const float*)d_in[4];
    const float* bk   = (const float*)d_in[5];
    const float* Wv   = (const float*)d_in[6];
    const float* bv   = (const float*)d_in[7];
    const float* Wp   = (const float*)d_in[8];
    const float* bp   = (const float*)d_in[9];
    float* out = (float*)d_out;

    short* ws    = (short*)d_ws;
    short* xb    = ws;                          // 4M shorts
    short* Wqkvt = xb + ((size_t)4 << 20);      // 3M
    short* Wpt   = Wqkvt + ((size_t)3 << 20);   // 1M
    short* Qb    = Wpt + ((size_t)1 << 20);     // 4M
    short* Kb    = Qb + ((size_t)4 << 20);      // 4M
    short* Vtb   = Kb + ((size_t)4 << 20);      // 4M
    short* Yb    = Vtb + ((size_t)4 << 20);     // 4M
    float* maskf = (float*)(Yb + ((size_t)4 << 20));  // 4096 floats

    const int M = BATCH * SEQ;  // 4096

    prep<<<dim3(6160), 256, 0, stream>>>(x, Wq, Wk, Wv, Wp, mask,
                                         xb, Wqkvt, Wpt, maskf);

    mfma_gemm<1><<<dim3(3 * D_MODEL / 128, M / 128), 256, 0, stream>>>(
        xb, Wqkvt, bq, bk, bv, nullptr, Qb, Kb, Vtb, M, 3 * D_MODEL, D_MODEL);

    flash_attn<<<dim3(BATCH * HEADS * (SEQ / QTILE)), 256, 0, stream>>>(Qb, Kb, Vtb, maskf, Yb);

    mfma_gemm<0><<<dim3(D_MODEL / 128, M / 128), 256, 0, stream>>>(
        Yb, Wpt, bp, bp, bp, out, nullptr, nullptr, nullptr, M, D_MODEL, D_MODEL);
}